// Round 1
// baseline (579.244 us; speedup 1.0000x reference)
//
#include <hip/hip_runtime.h>

// Row-wise L2-clip + noise:  out[r,:] = x[r,:] / max(||x[r,:]||_2, 1) + noise[r,:]
// (L2_NORM_CLIP = 1.0, noise multiplier already folded into the noise input.)
//
// Layout: D = 128 floats/row. One 32-lane half-wave per row, float4 per lane
// (16 B/lane). Pure streaming (768 MB, zero reuse) -> the only lever is
// sustained HBM BW. v2: each thread owns ROWS_PER_THREAD=4 rows (spaced
// `slots` apart so every unrolled iteration stays grid-contiguous) and
// batch-issues all 8 loads before any compute: 4x the memory-level
// parallelism per wave, 4x fewer waves (less launch/drain churn), and the
// four shfl-reduction chains are independent so the VALU interleaves them.
// Non-temporal hints on all three touch-once streams (evict-first policy).

constexpr int D = 128;
constexpr int ROWS_PER_THREAD = 4;

typedef float fv4 __attribute__((ext_vector_type(4)));

__global__ __launch_bounds__(256) void dp_clip_noise_kernel(
    const float* __restrict__ x,
    const float* __restrict__ noise,
    float* __restrict__ out,
    int slots)          // = n_rows / ROWS_PER_THREAD
{
    const int tid    = blockIdx.x * blockDim.x + threadIdx.x;
    const int slot   = tid >> 5;          // 32 lanes per row-slot
    const int lane32 = tid & 31;
    if (slot >= slots) return;

    long long base[ROWS_PER_THREAD];
    fv4 xa[ROWS_PER_THREAD];
    fv4 na[ROWS_PER_THREAD];

    // Batch-issue all x loads, then all noise loads: 8 outstanding 16 B
    // vector loads per thread before the first s_waitcnt.
#pragma unroll
    for (int i = 0; i < ROWS_PER_THREAD; ++i) {
        const long long row = (long long)slot + (long long)i * slots;
        base[i] = row * D + (long long)(lane32 * 4);
        xa[i] = __builtin_nontemporal_load(
            reinterpret_cast<const fv4*>(x + base[i]));
    }
#pragma unroll
    for (int i = 0; i < ROWS_PER_THREAD; ++i) {
        na[i] = __builtin_nontemporal_load(
            reinterpret_cast<const fv4*>(noise + base[i]));
    }

    // Four independent reduce->scale->fma->store chains; compiler is free
    // to interleave the shfl latencies across them.
#pragma unroll
    for (int i = 0; i < ROWS_PER_THREAD; ++i) {
        float s = xa[i].x * xa[i].x + xa[i].y * xa[i].y +
                  xa[i].z * xa[i].z + xa[i].w * xa[i].w;

        // xor offsets < 32 stay inside the half-wave on wave64
        s += __shfl_xor(s, 16, 64);
        s += __shfl_xor(s,  8, 64);
        s += __shfl_xor(s,  4, 64);
        s += __shfl_xor(s,  2, 64);
        s += __shfl_xor(s,  1, 64);

        const float norm  = sqrtf(s);
        const float scale = (norm > 1.0f) ? (1.0f / norm) : 1.0f;

        fv4 o;
        o.x = fmaf(xa[i].x, scale, na[i].x);
        o.y = fmaf(xa[i].y, scale, na[i].y);
        o.z = fmaf(xa[i].z, scale, na[i].z);
        o.w = fmaf(xa[i].w, scale, na[i].w);

        __builtin_nontemporal_store(o, reinterpret_cast<fv4*>(out + base[i]));
    }
}

extern "C" void kernel_launch(void* const* d_in, const int* in_sizes, int n_in,
                              void* d_out, int out_size, void* d_ws, size_t ws_size,
                              hipStream_t stream)
{
    const float* x     = (const float*)d_in[0];
    const float* noise = (const float*)d_in[1];
    float*       out   = (float*)d_out;

    const int n_rows = in_sizes[0] / D;            // 524288
    const int slots  = n_rows / ROWS_PER_THREAD;   // 131072 (N divisible by 4)

    // 32 threads per slot, 256 threads per block -> 8 slots/block
    const int total_threads = slots * 32;
    const int block = 256;
    const int grid  = (total_threads + block - 1) / block;

    dp_clip_noise_kernel<<<grid, block, 0, stream>>>(x, noise, out, slots);
}